// Round 1
// 155.429 us; speedup vs baseline: 1.0067x; 1.0067x over previous
//
#include <hip/hip_runtime.h>
#include <math.h>
#include <stdint.h>

#define PI_F 3.14159265358979323846f
#define HALF_PI_F 1.57079632679489662f

// Problem constants: B=32, N=200000, H=1024, W=2048
#define IMG_H 1024
#define IMG_W 2048
#define NB 8    // batches per thread

// Workspace layout:
//   floats [0, 9*B)   : rotation matrices Rm
//   floats [288, 320) : per-batch loss sums
//   floats [320, 352) : per-batch mask counts
//   bytes  [2048, +8MB): overlapping vertical-pair RGB565 image:
//     u32 vp[y*W + x] = lo: pix(y,x), hi: pix(min(y+1,H-1), x)

// 8-byte pair of adjacent vp words, 4-byte aligned (backend emits one
// global_load_dwordx2 when unaligned-access mode allows, else 2 dwords --
// both correct).
struct __attribute__((packed, aligned(4))) U2 { uint32_t a, b; };

__device__ __forceinline__ float fast_atan2f(float y, float x) {
    float ax = fabsf(x), ay = fabsf(y);
    float mx = fmaxf(ax, ay), mn = fminf(ax, ay);
    float a = __fdividef(mn, mx);
    float s = a * a;
    float r = fmaf(s, -0.01172120f, 0.05265332f);
    r = fmaf(s, r, -0.11643287f);
    r = fmaf(s, r, 0.19354346f);
    r = fmaf(s, r, -0.33262347f);
    r = fmaf(s, r, 0.99997726f);
    r = r * a;
    if (ay > ax) r = HALF_PI_F - r;
    if (x < 0.0f) r = PI_F - r;
    return copysignf(r, y);
}

__device__ __forceinline__ uint32_t quant565(const float* __restrict__ img, size_t pix) {
    float r = img[pix + 0], g = img[pix + 1], b = img[pix + 2];
    uint32_t r5 = min((uint32_t)__float2uint_rn(r * 31.0f), 31u);
    uint32_t g6 = min((uint32_t)__float2uint_rn(g * 63.0f), 63u);
    uint32_t b5 = min((uint32_t)__float2uint_rn(b * 31.0f), 31u);
    return (r5 << 11) | (g6 << 5) | b5;
}

// Pack f32 HWC image -> overlapping vertical-pair RGB565 u32; block 0 also does setup.
__global__ __launch_bounds__(256) void bsl_pack_setup(
        const float* __restrict__ img, uint32_t* __restrict__ vp,
        const float* __restrict__ yaw, const float* __restrict__ pitch,
        const float* __restrict__ roll, float* __restrict__ rm,
        float* __restrict__ sums, float* __restrict__ cnts, int B) {
    if (blockIdx.x == 0 && threadIdx.x < 32) {
        int b = threadIdx.x;
        if (b < B) {
            float cr = cosf(roll[b]),  sr = sinf(roll[b]);
            float cp = cosf(pitch[b]), sp = sinf(pitch[b]);
            float cy = cosf(yaw[b]),   sy = sinf(yaw[b]);
            float RX[9] = {1.f, 0.f, 0.f,   0.f, cr, -sr,   0.f, sr,  cr};
            float RY[9] = {cp,  0.f, sp,    0.f, 1.f, 0.f,  -sp, 0.f, cp};
            float RZ[9] = {cy, -sy, 0.f,    sy,  cy, 0.f,   0.f, 0.f, 1.f};
            float A[9], M[9];
            for (int i = 0; i < 3; ++i)
                for (int j = 0; j < 3; ++j) {
                    float s = 0.f;
                    for (int k = 0; k < 3; ++k) s += RZ[i*3+k] * RY[k*3+j];
                    A[i*3+j] = s;
                }
            for (int i = 0; i < 3; ++i)
                for (int j = 0; j < 3; ++j) {
                    float s = 0.f;
                    for (int k = 0; k < 3; ++k) s += A[i*3+k] * RX[k*3+j];
                    M[i*3+j] = s;
                }
            for (int k = 0; k < 9; ++k) rm[b*9+k] = M[k];
            sums[b] = 0.f;
            cnts[b] = 0.f;
        }
    }
    int idx = blockIdx.x * 256 + threadIdx.x;   // y*W + x
    if (idx < IMG_H * IMG_W) {
        int y = idx >> 11;                       // W = 2048
        int x = idx & (IMG_W - 1);
        int y1 = min(y + 1, IMG_H - 1);
        uint32_t lo = quant565(img, (size_t)idx * 3);
        uint32_t hi = quant565(img, ((size_t)y1 * IMG_W + x) * 3);
        vp[idx] = lo | (hi << 16);
    }
}

__global__ __launch_bounds__(256) void bsl_main(
        const float* __restrict__ xyz,
        const float* __restrict__ rgb,
        const uint32_t* __restrict__ vp,
        const float* __restrict__ trans,
        const float* __restrict__ rm,
        float* __restrict__ sums,
        float* __restrict__ cnts,
        int n_pts) {
    const int b0 = blockIdx.y * NB;
    const int tid = threadIdx.x;
    const int n = blockIdx.x * 256 + tid;

    float accs[NB], cnl[NB];
    #pragma unroll
    for (int nb = 0; nb < NB; ++nb) { accs[nb] = 0.f; cnl[nb] = 0.f; }

    if (n < n_pts) {
        // nontemporal: don't let the point streams evict the image from L2
        float px = __builtin_nontemporal_load(&xyz[3*n+0]);
        float py = __builtin_nontemporal_load(&xyz[3*n+1]);
        float pz = __builtin_nontemporal_load(&xyz[3*n+2]);
        float r0 = __builtin_nontemporal_load(&rgb[3*n+0]);
        float r1 = __builtin_nontemporal_load(&rgb[3*n+1]);
        float r2 = __builtin_nontemporal_load(&rgb[3*n+2]);

        // Phase 1: compute coords for all NB batches, issue all NB pair
        // loads (8 independent gathers in flight per wave).
        float xfa[NB], yfa[NB];
        U2 pr[NB];
        #pragma unroll
        for (int nb = 0; nb < NB; ++nb) {
            const int b = b0 + nb;
            const float* R = rm + b * 9;        // block-uniform -> s_load
            const float* T = trans + b * 3;
            float qx = px - T[0], qy = py - T[1], qz = pz - T[2];

            float vx = R[0]*qx + R[1]*qy + R[2]*qz;
            float vy = R[3]*qx + R[4]*qy + R[5]*qz;
            float vz = R[6]*qx + R[7]*qy + R[8]*qz;

            float rxy   = sqrtf(vx*vx + vy*vy);
            float theta = fast_atan2f(rxy, vz);     // [0, pi]
            float praw  = fast_atan2f(vy, vx);      // (-pi, pi]

            // xf = 1023.5 - 1024*praw/pi ; yf = 1024*theta/pi - 0.5
            float xf = fmaf(praw,  -325.949323452f, 1023.5f);
            float yf = fmaf(theta,  325.949323452f, -0.5f);
            xfa[nb] = xf;
            yfa[nb] = yf;

            // base column clamped to [0,2046] so the pair (xb, xb+1) is
            // always in-bounds; x0=2047 / x0=-1 fixed up in phase 2.
            float xbf = fminf(fmaxf(floorf(xf), 0.0f), 2046.0f);
            float ybf = fminf(fmaxf(floorf(yf), 0.0f), 1023.0f);
            int xb = (int)xbf;
            int yb = (int)ybf;
            pr[nb] = *(const U2*)(vp + ((yb << 11) + xb));
        }

        // Phase 2: decode + blend + accumulate.
        #pragma unroll
        for (int nb = 0; nb < NB; ++nb) {
            float xf = xfa[nb], yf = yfa[nb];
            float x0f = floorf(xf), y0f = floorf(yf);
            float wx = xf - x0f, wy = yf - y0f;

            // validity, all as float compares (x0 in [-1,2047], y0 in [-1,1023])
            bool vx0 = (x0f >= 0.0f);       // x0 valid
            bool vx1 = (x0f <= 2046.0f);    // x0+1 valid
            bool vy0 = (y0f >= 0.0f);       // y0 valid
            bool vy1 = (y0f <= 1022.0f);    // y0+1 valid

            float omx = 1.0f - wx, omy = 1.0f - wy;
            float w00 = (vx0 & vy0) ? omx * omy : 0.0f;
            float w10 = (vx1 & vy0) ? wx  * omy : 0.0f;
            float w01 = (vx0 & vy1) ? omx * wy  : 0.0f;
            float w11 = (vx1 & vy1) ? wx  * wy  : 0.0f;

            uint32_t pa = pr[nb].a, pb = pr[nb].b;
            // x0==2047: base was clamped to 2046, col 2047 = pb (x1c==2047 too)
            uint32_t wAv = (x0f >= 2047.0f) ? pb : pa;
            // x0==-1: base 0, t10 must be col 0 = pa (wA weights are 0)
            uint32_t wBv = vx0 ? pb : pa;

            uint32_t t00 = wAv & 0xffffu;
            uint32_t t10 = wBv & 0xffffu;
            uint32_t t01 = vy0 ? (wAv >> 16) : t00;
            uint32_t t11 = vy0 ? (wBv >> 16) : t10;

            // integer-valued float channels; fold 1/31,1/63 into the final fma
            float r00 = (float)(t00 >> 11),        r10 = (float)(t10 >> 11);
            float r01 = (float)(t01 >> 11),        r11 = (float)(t11 >> 11);
            float g00 = (float)((t00 >> 5) & 63u), g10 = (float)((t10 >> 5) & 63u);
            float g01 = (float)((t01 >> 5) & 63u), g11 = (float)((t11 >> 5) & 63u);
            float b00 = (float)(t00 & 31u),        b10 = (float)(t10 & 31u);
            float b01 = (float)(t01 & 31u),        b11 = (float)(t11 & 31u);

            float sr = r00*w00 + r10*w10 + r01*w01 + r11*w11;
            float sg = g00*w00 + g10*w10 + g01*w01 + g11*w11;
            float sb = b00*w00 + b10*w10 + b01*w01 + b11*w11;

            bool m = !((sr == 0.0f) && (sg == 0.0f) && (sb == 0.0f));

            float d0 = fmaf(sr, 1.0f / 31.0f, -r0);
            float d1 = fmaf(sg, 1.0f / 63.0f, -r1);
            float d2 = fmaf(sb, 1.0f / 31.0f, -r2);
            float per = sqrtf(d0*d0 + d1*d1 + d2*d2);

            accs[nb] += m ? per : 0.0f;
            cnl[nb]  += m ? 1.0f : 0.0f;
        }
    }

    // wave(64) shuffle reduce per batch, then LDS across 4 waves, then atomics
    __shared__ float lsum[4][NB], lcnt[4][NB];
    int wid = tid >> 6;
    int lane = tid & 63;
    #pragma unroll
    for (int nb = 0; nb < NB; ++nb) {
        float a = accs[nb], c = cnl[nb];
        #pragma unroll
        for (int off = 32; off > 0; off >>= 1) {
            a += __shfl_down(a, off, 64);
            c += __shfl_down(c, off, 64);
        }
        if (lane == 0) { lsum[wid][nb] = a; lcnt[wid][nb] = c; }
    }
    __syncthreads();
    if (tid < NB * 2) {
        int nb = tid & (NB - 1);
        int k = tid >> 3;   // 0 = sum, 1 = cnt
        float v = 0.f;
        #pragma unroll
        for (int w = 0; w < 4; ++w) v += k ? lcnt[w][nb] : lsum[w][nb];
        atomicAdd(k ? &cnts[b0 + nb] : &sums[b0 + nb], v);
    }
}

__global__ void bsl_finalize(const float* __restrict__ sums,
                             const float* __restrict__ cnts,
                             float* __restrict__ out,
                             int B) {
    int b = threadIdx.x;  // 0..63
    float loss = 0.f;
    if (b < B) {
        loss = sums[b] / cnts[b];
        out[1 + b] = loss;
    }
    #pragma unroll
    for (int off = 32; off > 0; off >>= 1)
        loss += __shfl_down(loss, off, 64);
    if (b == 0) out[0] = loss;
}

extern "C" void kernel_launch(void* const* d_in, const int* in_sizes, int n_in,
                              void* d_out, int out_size, void* d_ws, size_t ws_size,
                              hipStream_t stream) {
    const float* xyz   = (const float*)d_in[0];
    const float* rgb   = (const float*)d_in[1];
    const float* img   = (const float*)d_in[2];
    const float* trans = (const float*)d_in[3];
    const float* yaw   = (const float*)d_in[4];
    const float* pitch = (const float*)d_in[5];
    const float* roll  = (const float*)d_in[6];
    float* out = (float*)d_out;

    const int n_pts = in_sizes[0] / 3;      // 200000
    const int B     = in_sizes[3] / 3;      // 32

    float* ws   = (float*)d_ws;
    float* rm   = ws;               // 9*B floats
    float* sums = ws + 9 * B;       // B floats
    float* cnts = ws + 10 * B;      // B floats
    uint32_t* vp = (uint32_t*)((char*)d_ws + 2048);  // 8 MB

    bsl_pack_setup<<<(IMG_H * IMG_W + 255) / 256, 256, 0, stream>>>(
        img, vp, yaw, pitch, roll, rm, sums, cnts, B);

    dim3 grid((n_pts + 255) / 256, B / NB);
    bsl_main<<<grid, 256, 0, stream>>>(xyz, rgb, vp, trans, rm, sums, cnts, n_pts);

    bsl_finalize<<<1, 64, 0, stream>>>(sums, cnts, out, B);
}

// Round 2
// 150.706 us; speedup vs baseline: 1.0382x; 1.0313x over previous
//
#include <hip/hip_runtime.h>
#include <math.h>
#include <stdint.h>

#define PI_F 3.14159265358979323846f
#define HALF_PI_F 1.57079632679489662f

// Problem constants: B=32, N=200000, H=1024, W=2048
#define IMG_H 1024
#define IMG_W 2048
#define NB 8    // batches per thread

// Workspace layout:
//   floats [0, 9*B)   : rotation matrices Rm
//   floats [288, 320) : per-batch loss sums
//   floats [320, 352) : per-batch mask counts
//   bytes  [2048, +4MB): NON-overlapping even/odd row-pair RGB565 image:
//     u32 vp2[(y>>1)*W + x] = lo: pix(2k, x), hi: pix(2k+1, x)
//   -> 512*2048*4 = 4 MB: fits a per-XCD L2 (4 MB), unlike the old 8 MB
//      overlapping layout which guaranteed L2 thrash on random gathers.

// 8-byte pair of adjacent vp2 words, 4-byte aligned.
struct __attribute__((packed, aligned(4))) U2 { uint32_t a, b; };

__device__ __forceinline__ float fast_atan2f(float y, float x) {
    float ax = fabsf(x), ay = fabsf(y);
    float mx = fmaxf(ax, ay), mn = fminf(ax, ay);
    float a = __fdividef(mn, mx);
    float s = a * a;
    float r = fmaf(s, -0.01172120f, 0.05265332f);
    r = fmaf(s, r, -0.11643287f);
    r = fmaf(s, r, 0.19354346f);
    r = fmaf(s, r, -0.33262347f);
    r = fmaf(s, r, 0.99997726f);
    r = r * a;
    if (ay > ax) r = HALF_PI_F - r;
    if (x < 0.0f) r = PI_F - r;
    return copysignf(r, y);
}

__device__ __forceinline__ uint32_t q565(float r, float g, float b) {
    uint32_t r5 = min((uint32_t)__float2uint_rn(r * 31.0f), 31u);
    uint32_t g6 = min((uint32_t)__float2uint_rn(g * 63.0f), 63u);
    uint32_t b5 = min((uint32_t)__float2uint_rn(b * 31.0f), 31u);
    return (r5 << 11) | (g6 << 5) | b5;
}

// Pack f32 HWC image -> even/odd row-pair RGB565 u32; block 0 also does setup.
// Each thread: 4 adjacent output words = 4 pixels from row 2k and 4 from row
// 2k+1, via 6 coalesced float4 loads + one uint4 store.
__global__ __launch_bounds__(256) void bsl_pack_setup(
        const float* __restrict__ img, uint32_t* __restrict__ vp2,
        const float* __restrict__ yaw, const float* __restrict__ pitch,
        const float* __restrict__ roll, float* __restrict__ rm,
        float* __restrict__ sums, float* __restrict__ cnts, int B) {
    if (blockIdx.x == 0 && threadIdx.x < 32) {
        int b = threadIdx.x;
        if (b < B) {
            float cr = cosf(roll[b]),  sr = sinf(roll[b]);
            float cp = cosf(pitch[b]), sp = sinf(pitch[b]);
            float cy = cosf(yaw[b]),   sy = sinf(yaw[b]);
            float RX[9] = {1.f, 0.f, 0.f,   0.f, cr, -sr,   0.f, sr,  cr};
            float RY[9] = {cp,  0.f, sp,    0.f, 1.f, 0.f,  -sp, 0.f, cp};
            float RZ[9] = {cy, -sy, 0.f,    sy,  cy, 0.f,   0.f, 0.f, 1.f};
            float A[9], M[9];
            for (int i = 0; i < 3; ++i)
                for (int j = 0; j < 3; ++j) {
                    float s = 0.f;
                    for (int k = 0; k < 3; ++k) s += RZ[i*3+k] * RY[k*3+j];
                    A[i*3+j] = s;
                }
            for (int i = 0; i < 3; ++i)
                for (int j = 0; j < 3; ++j) {
                    float s = 0.f;
                    for (int k = 0; k < 3; ++k) s += A[i*3+k] * RX[k*3+j];
                    M[i*3+j] = s;
                }
            for (int k = 0; k < 9; ++k) rm[b*9+k] = M[k];
            sums[b] = 0.f;
            cnts[b] = 0.f;
        }
    }
    int t = blockIdx.x * 256 + threadIdx.x;     // 262144 threads total
    if (t < (IMG_H / 2) * (IMG_W / 4)) {
        int y2 = t >> 9;                        // 512 threads per row-pair
        int xq = (t & 511) << 2;                // x, x+1, x+2, x+3
        const float4* r0 = (const float4*)(img + ((size_t)(2 * y2) * IMG_W + xq) * 3);
        const float4* r1 = (const float4*)(img + ((size_t)(2 * y2 + 1) * IMG_W + xq) * 3);
        float4 a0 = r0[0], a1 = r0[1], a2 = r0[2];
        float4 b0 = r1[0], b1 = r1[1], b2 = r1[2];
        uint32_t lo0 = q565(a0.x, a0.y, a0.z);
        uint32_t lo1 = q565(a0.w, a1.x, a1.y);
        uint32_t lo2 = q565(a1.z, a1.w, a2.x);
        uint32_t lo3 = q565(a2.y, a2.z, a2.w);
        uint32_t hi0 = q565(b0.x, b0.y, b0.z);
        uint32_t hi1 = q565(b0.w, b1.x, b1.y);
        uint32_t hi2 = q565(b1.z, b1.w, b2.x);
        uint32_t hi3 = q565(b2.y, b2.z, b2.w);
        uint4 outv;
        outv.x = lo0 | (hi0 << 16);
        outv.y = lo1 | (hi1 << 16);
        outv.z = lo2 | (hi2 << 16);
        outv.w = lo3 | (hi3 << 16);
        *(uint4*)(vp2 + ((size_t)y2 * IMG_W + xq)) = outv;
    }
}

__global__ __launch_bounds__(256) void bsl_main(
        const float* __restrict__ xyz,
        const float* __restrict__ rgb,
        const uint32_t* __restrict__ vp2,
        const float* __restrict__ trans,
        const float* __restrict__ rm,
        float* __restrict__ sums,
        float* __restrict__ cnts,
        int n_pts) {
    const int b0 = blockIdx.y * NB;
    const int tid = threadIdx.x;
    const int n = blockIdx.x * 256 + tid;

    float accs[NB], cnl[NB];
    #pragma unroll
    for (int nb = 0; nb < NB; ++nb) { accs[nb] = 0.f; cnl[nb] = 0.f; }

    if (n < n_pts) {
        // nontemporal: don't let the point streams evict the image from L2
        float px = __builtin_nontemporal_load(&xyz[3*n+0]);
        float py = __builtin_nontemporal_load(&xyz[3*n+1]);
        float pz = __builtin_nontemporal_load(&xyz[3*n+2]);
        float r0 = __builtin_nontemporal_load(&rgb[3*n+0]);
        float r1 = __builtin_nontemporal_load(&rgb[3*n+1]);
        float r2 = __builtin_nontemporal_load(&rgb[3*n+2]);

        // Phase 1: compute coords for all NB batches, issue all 2*NB pair
        // loads (16 independent gathers in flight per wave).
        float xfa[NB], yfa[NB];
        U2 pA[NB], pB[NB];
        #pragma unroll
        for (int nb = 0; nb < NB; ++nb) {
            const int b = b0 + nb;
            const float* R = rm + b * 9;        // block-uniform -> s_load
            const float* T = trans + b * 3;
            float qx = px - T[0], qy = py - T[1], qz = pz - T[2];

            float vx = R[0]*qx + R[1]*qy + R[2]*qz;
            float vy = R[3]*qx + R[4]*qy + R[5]*qz;
            float vz = R[6]*qx + R[7]*qy + R[8]*qz;

            float rxy   = sqrtf(vx*vx + vy*vy);
            float theta = fast_atan2f(rxy, vz);     // [0, pi]
            float praw  = fast_atan2f(vy, vx);      // (-pi, pi]

            // xf = 1023.5 - 1024*praw/pi ; yf = 1024*theta/pi - 0.5
            float xf = fmaf(praw,  -325.949323452f, 1023.5f);
            float yf = fmaf(theta,  325.949323452f, -0.5f);
            xfa[nb] = xf;
            yfa[nb] = yf;

            float x0f = floorf(xf);
            float y0f = floorf(yf);
            // base column clamped to [0,2046] so pair (xb, xb+1) is in-bounds
            float xbf  = fminf(fmaxf(x0f, 0.0f), 2046.0f);
            float yb0f = fminf(fmaxf(y0f,        0.0f), 1023.0f);
            float yb1f = fminf(fmaxf(y0f + 1.0f, 0.0f), 1023.0f);
            int xb  = (int)xbf;
            int y0c = (int)yb0f;
            int y1c = (int)yb1f;
            // row-pair words: vp2[(y>>1)*2048 + xb], cols xb, xb+1
            pA[nb] = *(const U2*)(vp2 + (((y0c >> 1) << 11) + xb));
            pB[nb] = *(const U2*)(vp2 + (((y1c >> 1) << 11) + xb));
        }

        // Fence: forbid the compiler from sinking the gathers back into the
        // decode loop (round-1 failure mode: loops re-fused, 1-2 loads in
        // flight, VGPR stayed 32).
        asm volatile("" ::: "memory");

        // Phase 2: decode + blend + accumulate.
        #pragma unroll
        for (int nb = 0; nb < NB; ++nb) {
            float xf = xfa[nb], yf = yfa[nb];
            float x0f = floorf(xf), y0f = floorf(yf);
            float wx = xf - x0f, wy = yf - y0f;

            // validity, all as float compares (x0 in [-1,2047], y0 in [-1,1023])
            bool vx0 = (x0f >= 0.0f);       // x0 valid
            bool vx1 = (x0f <= 2046.0f);    // x0+1 valid
            bool vy0 = (y0f >= 0.0f);       // y0 valid
            bool vy1 = (y0f <= 1022.0f);    // y0+1 valid

            float omx = 1.0f - wx, omy = 1.0f - wy;
            float w00 = (vx0 & vy0) ? omx * omy : 0.0f;
            float w10 = (vx1 & vy0) ? wx  * omy : 0.0f;
            float w01 = (vx0 & vy1) ? omx * wy  : 0.0f;
            float w11 = (vx1 & vy1) ? wx  * wy  : 0.0f;

            // row parities select the 16-bit half of each pair word
            int y0c = (int)fminf(fmaxf(y0f,        0.0f), 1023.0f);
            int y1c = (int)fminf(fmaxf(y0f + 1.0f, 0.0f), 1023.0f);
            uint32_t sh0 = (uint32_t)(y0c & 1) << 4;
            uint32_t sh1 = (uint32_t)(y1c & 1) << 4;

            // column fixups (same as verified previous version):
            // x0==2047: base clamped to 2046 -> col x0 is .b (x1 weights are 0)
            // x0==-1:   base 0 -> col x1 is .a (x0 weights are 0)
            bool xhi = (x0f >= 2047.0f);
            uint32_t A0 = xhi ? pA[nb].b : pA[nb].a;    // (y0 row-pair, col x0)
            uint32_t A1 = vx0 ? pA[nb].b : pA[nb].a;    // (y0 row-pair, col x1)
            uint32_t B0 = xhi ? pB[nb].b : pB[nb].a;    // (y1 row-pair, col x0)
            uint32_t B1 = vx0 ? pB[nb].b : pB[nb].a;    // (y1 row-pair, col x1)

            uint32_t t00 = (A0 >> sh0) & 0xffffu;
            uint32_t t10 = (A1 >> sh0) & 0xffffu;
            uint32_t t01 = (B0 >> sh1) & 0xffffu;
            uint32_t t11 = (B1 >> sh1) & 0xffffu;

            // integer-valued float channels; fold 1/31,1/63 into the final fma
            float r00 = (float)(t00 >> 11),        r10 = (float)(t10 >> 11);
            float r01 = (float)(t01 >> 11),        r11 = (float)(t11 >> 11);
            float g00 = (float)((t00 >> 5) & 63u), g10 = (float)((t10 >> 5) & 63u);
            float g01 = (float)((t01 >> 5) & 63u), g11 = (float)((t11 >> 5) & 63u);
            float b00 = (float)(t00 & 31u),        b10 = (float)(t10 & 31u);
            float b01 = (float)(t01 & 31u),        b11 = (float)(t11 & 31u);

            float sr = r00*w00 + r10*w10 + r01*w01 + r11*w11;
            float sg = g00*w00 + g10*w10 + g01*w01 + g11*w11;
            float sb = b00*w00 + b10*w10 + b01*w01 + b11*w11;

            bool m = !((sr == 0.0f) && (sg == 0.0f) && (sb == 0.0f));

            float d0 = fmaf(sr, 1.0f / 31.0f, -r0);
            float d1 = fmaf(sg, 1.0f / 63.0f, -r1);
            float d2 = fmaf(sb, 1.0f / 31.0f, -r2);
            float per = sqrtf(d0*d0 + d1*d1 + d2*d2);

            accs[nb] += m ? per : 0.0f;
            cnl[nb]  += m ? 1.0f : 0.0f;
        }
    }

    // wave(64) shuffle reduce per batch, then LDS across 4 waves, then atomics
    __shared__ float lsum[4][NB], lcnt[4][NB];
    int wid = tid >> 6;
    int lane = tid & 63;
    #pragma unroll
    for (int nb = 0; nb < NB; ++nb) {
        float a = accs[nb], c = cnl[nb];
        #pragma unroll
        for (int off = 32; off > 0; off >>= 1) {
            a += __shfl_down(a, off, 64);
            c += __shfl_down(c, off, 64);
        }
        if (lane == 0) { lsum[wid][nb] = a; lcnt[wid][nb] = c; }
    }
    __syncthreads();
    if (tid < NB * 2) {
        int nb = tid & (NB - 1);
        int k = tid >> 3;   // 0 = sum, 1 = cnt
        float v = 0.f;
        #pragma unroll
        for (int w = 0; w < 4; ++w) v += k ? lcnt[w][nb] : lsum[w][nb];
        atomicAdd(k ? &cnts[b0 + nb] : &sums[b0 + nb], v);
    }
}

__global__ void bsl_finalize(const float* __restrict__ sums,
                             const float* __restrict__ cnts,
                             float* __restrict__ out,
                             int B) {
    int b = threadIdx.x;  // 0..63
    float loss = 0.f;
    if (b < B) {
        loss = sums[b] / cnts[b];
        out[1 + b] = loss;
    }
    #pragma unroll
    for (int off = 32; off > 0; off >>= 1)
        loss += __shfl_down(loss, off, 64);
    if (b == 0) out[0] = loss;
}

extern "C" void kernel_launch(void* const* d_in, const int* in_sizes, int n_in,
                              void* d_out, int out_size, void* d_ws, size_t ws_size,
                              hipStream_t stream) {
    const float* xyz   = (const float*)d_in[0];
    const float* rgb   = (const float*)d_in[1];
    const float* img   = (const float*)d_in[2];
    const float* trans = (const float*)d_in[3];
    const float* yaw   = (const float*)d_in[4];
    const float* pitch = (const float*)d_in[5];
    const float* roll  = (const float*)d_in[6];
    float* out = (float*)d_out;

    const int n_pts = in_sizes[0] / 3;      // 200000
    const int B     = in_sizes[3] / 3;      // 32

    float* ws   = (float*)d_ws;
    float* rm   = ws;               // 9*B floats
    float* sums = ws + 9 * B;       // B floats
    float* cnts = ws + 10 * B;      // B floats
    uint32_t* vp2 = (uint32_t*)((char*)d_ws + 2048);  // 4 MB

    bsl_pack_setup<<<((IMG_H / 2) * (IMG_W / 4) + 255) / 256, 256, 0, stream>>>(
        img, vp2, yaw, pitch, roll, rm, sums, cnts, B);

    dim3 grid((n_pts + 255) / 256, B / NB);
    bsl_main<<<grid, 256, 0, stream>>>(xyz, rgb, vp2, trans, rm, sums, cnts, n_pts);

    bsl_finalize<<<1, 64, 0, stream>>>(sums, cnts, out, B);
}

// Round 3
// 148.231 us; speedup vs baseline: 1.0555x; 1.0167x over previous
//
#include <hip/hip_runtime.h>
#include <math.h>
#include <stdint.h>

#define PI_F 3.14159265358979323846f
#define HALF_PI_F 1.57079632679489662f

// Problem constants: B=32, N=200000, H=1024, W=2048
#define IMG_H 1024
#define IMG_W 2048
#define NB 8    // batches per thread

// Workspace layout:
//   floats [0, 9*B)   : rotation matrices Rm
//   floats [288, 320) : per-batch loss sums
//   floats [320, 352) : per-batch mask counts
//   bytes  [2048, +4MB): NON-overlapping even/odd row-pair RGB565 image:
//     u32 vp2[(y>>1)*W + x] = lo: pix(2k, x), hi: pix(2k+1, x)
//   -> 4 MB: fits per-XCD L2 (verified round 2: FETCH 184MB -> 27MB)

// 8-byte pair of adjacent vp2 words, 4-byte aligned.
struct __attribute__((packed, aligned(4))) U2 { uint32_t a, b; };

__device__ __forceinline__ float fast_atan2f(float y, float x) {
    float ax = fabsf(x), ay = fabsf(y);
    float mx = fmaxf(ax, ay), mn = fminf(ax, ay);
    float a = __fdividef(mn, mx);
    float s = a * a;
    float r = fmaf(s, -0.01172120f, 0.05265332f);
    r = fmaf(s, r, -0.11643287f);
    r = fmaf(s, r, 0.19354346f);
    r = fmaf(s, r, -0.33262347f);
    r = fmaf(s, r, 0.99997726f);
    r = r * a;
    if (ay > ax) r = HALF_PI_F - r;
    if (x < 0.0f) r = PI_F - r;
    return copysignf(r, y);
}

__device__ __forceinline__ uint32_t q565(float r, float g, float b) {
    uint32_t r5 = min((uint32_t)__float2uint_rn(r * 31.0f), 31u);
    uint32_t g6 = min((uint32_t)__float2uint_rn(g * 63.0f), 63u);
    uint32_t b5 = min((uint32_t)__float2uint_rn(b * 31.0f), 31u);
    return (r5 << 11) | (g6 << 5) | b5;
}

// Pack f32 HWC image -> even/odd row-pair RGB565 u32; block 0 also does setup.
__global__ __launch_bounds__(256) void bsl_pack_setup(
        const float* __restrict__ img, uint32_t* __restrict__ vp2,
        const float* __restrict__ yaw, const float* __restrict__ pitch,
        const float* __restrict__ roll, float* __restrict__ rm,
        float* __restrict__ sums, float* __restrict__ cnts, int B) {
    if (blockIdx.x == 0 && threadIdx.x < 32) {
        int b = threadIdx.x;
        if (b < B) {
            float cr = cosf(roll[b]),  sr = sinf(roll[b]);
            float cp = cosf(pitch[b]), sp = sinf(pitch[b]);
            float cy = cosf(yaw[b]),   sy = sinf(yaw[b]);
            float RX[9] = {1.f, 0.f, 0.f,   0.f, cr, -sr,   0.f, sr,  cr};
            float RY[9] = {cp,  0.f, sp,    0.f, 1.f, 0.f,  -sp, 0.f, cp};
            float RZ[9] = {cy, -sy, 0.f,    sy,  cy, 0.f,   0.f, 0.f, 1.f};
            float A[9], M[9];
            for (int i = 0; i < 3; ++i)
                for (int j = 0; j < 3; ++j) {
                    float s = 0.f;
                    for (int k = 0; k < 3; ++k) s += RZ[i*3+k] * RY[k*3+j];
                    A[i*3+j] = s;
                }
            for (int i = 0; i < 3; ++i)
                for (int j = 0; j < 3; ++j) {
                    float s = 0.f;
                    for (int k = 0; k < 3; ++k) s += A[i*3+k] * RX[k*3+j];
                    M[i*3+j] = s;
                }
            for (int k = 0; k < 9; ++k) rm[b*9+k] = M[k];
            sums[b] = 0.f;
            cnts[b] = 0.f;
        }
    }
    int t = blockIdx.x * 256 + threadIdx.x;     // 262144 threads total
    if (t < (IMG_H / 2) * (IMG_W / 4)) {
        int y2 = t >> 9;                        // 512 threads per row-pair
        int xq = (t & 511) << 2;                // x, x+1, x+2, x+3
        const float4* r0 = (const float4*)(img + ((size_t)(2 * y2) * IMG_W + xq) * 3);
        const float4* r1 = (const float4*)(img + ((size_t)(2 * y2 + 1) * IMG_W + xq) * 3);
        float4 a0 = r0[0], a1 = r0[1], a2 = r0[2];
        float4 b0 = r1[0], b1 = r1[1], b2 = r1[2];
        uint32_t lo0 = q565(a0.x, a0.y, a0.z);
        uint32_t lo1 = q565(a0.w, a1.x, a1.y);
        uint32_t lo2 = q565(a1.z, a1.w, a2.x);
        uint32_t lo3 = q565(a2.y, a2.z, a2.w);
        uint32_t hi0 = q565(b0.x, b0.y, b0.z);
        uint32_t hi1 = q565(b0.w, b1.x, b1.y);
        uint32_t hi2 = q565(b1.z, b1.w, b2.x);
        uint32_t hi3 = q565(b2.y, b2.z, b2.w);
        uint4 outv;
        outv.x = lo0 | (hi0 << 16);
        outv.y = lo1 | (hi1 << 16);
        outv.z = lo2 | (hi2 << 16);
        outv.w = lo3 | (hi3 << 16);
        *(uint4*)(vp2 + ((size_t)y2 * IMG_W + xq)) = outv;
    }
}

__global__ __launch_bounds__(256, 4) void bsl_main(
        const float* __restrict__ xyz,
        const float* __restrict__ rgb,
        const uint32_t* __restrict__ vp2,
        const float* __restrict__ trans,
        const float* __restrict__ rm,
        float* __restrict__ sums,
        float* __restrict__ cnts,
        int n_pts) {
    const int b0 = blockIdx.y * NB;
    const int tid = threadIdx.x;
    const int n = blockIdx.x * 256 + tid;

    float accs[NB], cnl[NB];
    #pragma unroll
    for (int nb = 0; nb < NB; ++nb) { accs[nb] = 0.f; cnl[nb] = 0.f; }

    if (n < n_pts) {
        // nontemporal: don't let the point streams evict the image from L2
        float px = __builtin_nontemporal_load(&xyz[3*n+0]);
        float py = __builtin_nontemporal_load(&xyz[3*n+1]);
        float pz = __builtin_nontemporal_load(&xyz[3*n+2]);
        float r0 = __builtin_nontemporal_load(&rgb[3*n+0]);
        float r1 = __builtin_nontemporal_load(&rgb[3*n+1]);
        float r2 = __builtin_nontemporal_load(&rgb[3*n+2]);

        // Phase 1: compute coords for all NB batches, issue all 2*NB pair
        // loads. State to phase 2: pair words, x0f (via xfa), wx, wy, and
        // shp = {sh0, sh1, vy0, vy1} packed.
        float xfa[NB], wxa[NB], wya[NB];
        uint32_t shp[NB];
        uint32_t pAa[NB], pAb[NB], pBa[NB], pBb[NB];
        #pragma unroll
        for (int nb = 0; nb < NB; ++nb) {
            const int b = b0 + nb;
            const float* R = rm + b * 9;        // block-uniform -> s_load
            const float* T = trans + b * 3;
            float qx = px - T[0], qy = py - T[1], qz = pz - T[2];

            float vx = R[0]*qx + R[1]*qy + R[2]*qz;
            float vy = R[3]*qx + R[4]*qy + R[5]*qz;
            float vz = R[6]*qx + R[7]*qy + R[8]*qz;

            float rxy   = sqrtf(vx*vx + vy*vy);
            float theta = fast_atan2f(rxy, vz);     // [0, pi]
            float praw  = fast_atan2f(vy, vx);      // (-pi, pi]

            // xf = 1023.5 - 1024*praw/pi ; yf = 1024*theta/pi - 0.5
            float xf = fmaf(praw,  -325.949323452f, 1023.5f);
            float yf = fmaf(theta,  325.949323452f, -0.5f);

            float x0f = floorf(xf);
            float y0f = floorf(yf);
            xfa[nb] = xf;
            wxa[nb] = xf - x0f;
            wya[nb] = yf - y0f;

            // base column clamped to [0,2046] so pair (xb, xb+1) is in-bounds
            float xbf  = fminf(fmaxf(x0f, 0.0f), 2046.0f);
            float yb0f = fminf(fmaxf(y0f,        0.0f), 1023.0f);
            float yb1f = fminf(fmaxf(y0f + 1.0f, 0.0f), 1023.0f);
            int xb  = (int)xbf;
            int y0c = (int)yb0f;
            int y1c = (int)yb1f;
            uint32_t sp = ((uint32_t)(y0c & 1) << 4) | ((uint32_t)(y1c & 1) << 12);
            if (y0f >= 0.0f)    sp |= 1u << 24;     // vy0
            if (y0f <= 1022.0f) sp |= 1u << 25;     // vy1
            shp[nb] = sp;

            // row-pair words: vp2[(y>>1)*2048 + xb], cols xb, xb+1
            U2 tA = *(const U2*)(vp2 + (((y0c >> 1) << 11) + xb));
            U2 tB = *(const U2*)(vp2 + (((y1c >> 1) << 11) + xb));
            pAa[nb] = tA.a; pAb[nb] = tA.b;
            pBa[nb] = tB.a; pBb[nb] = tB.b;
        }

        // MLP fence: pin every loaded word in a VGPR at this point (memory
        // clobber stops load sinking; "+v" forces all 32 results to coexist,
        // so all 16 pair-loads must be issued before the first consume).
        // Gate for this round: VGPR must jump from 36 to ~100.
        #pragma unroll
        for (int nb = 0; nb < NB; ++nb) {
            asm volatile("" : "+v"(pAa[nb]), "+v"(pAb[nb]),
                             "+v"(pBa[nb]), "+v"(pBb[nb]) :: "memory");
        }

        // Phase 2: decode + blend + accumulate.
        #pragma unroll
        for (int nb = 0; nb < NB; ++nb) {
            float xf = xfa[nb];
            float x0f = floorf(xf);
            float wx = wxa[nb], wy = wya[nb];

            bool vx0 = (x0f >= 0.0f);       // x0 valid
            bool vx1 = (x0f <= 2046.0f);    // x0+1 valid
            uint32_t sp = shp[nb];
            bool vy0 = (sp & (1u << 24)) != 0u;
            bool vy1 = (sp & (1u << 25)) != 0u;

            float omx = 1.0f - wx, omy = 1.0f - wy;
            float w00 = (vx0 & vy0) ? omx * omy : 0.0f;
            float w10 = (vx1 & vy0) ? wx  * omy : 0.0f;
            float w01 = (vx0 & vy1) ? omx * wy  : 0.0f;
            float w11 = (vx1 & vy1) ? wx  * wy  : 0.0f;

            uint32_t sh0 = sp & 0xffu;
            uint32_t sh1 = (sp >> 8) & 0xffu;

            // column fixups:
            // x0==2047: base clamped to 2046 -> col x0 is .b (x1 weights are 0)
            // x0==-1:   base 0 -> col x1 is .a (x0 weights are 0)
            bool xhi = (x0f >= 2047.0f);
            uint32_t A0 = xhi ? pAb[nb] : pAa[nb];    // (y0 row-pair, col x0)
            uint32_t A1 = vx0 ? pAb[nb] : pAa[nb];    // (y0 row-pair, col x1)
            uint32_t B0 = xhi ? pBb[nb] : pBa[nb];    // (y1 row-pair, col x0)
            uint32_t B1 = vx0 ? pBb[nb] : pBa[nb];    // (y1 row-pair, col x1)

            uint32_t t00 = (A0 >> sh0) & 0xffffu;
            uint32_t t10 = (A1 >> sh0) & 0xffffu;
            uint32_t t01 = (B0 >> sh1) & 0xffffu;
            uint32_t t11 = (B1 >> sh1) & 0xffffu;

            // integer-valued float channels; fold 1/31,1/63 into the final fma
            float r00 = (float)(t00 >> 11),        r10 = (float)(t10 >> 11);
            float r01 = (float)(t01 >> 11),        r11 = (float)(t11 >> 11);
            float g00 = (float)((t00 >> 5) & 63u), g10 = (float)((t10 >> 5) & 63u);
            float g01 = (float)((t01 >> 5) & 63u), g11 = (float)((t11 >> 5) & 63u);
            float b00 = (float)(t00 & 31u),        b10 = (float)(t10 & 31u);
            float b01 = (float)(t01 & 31u),        b11 = (float)(t11 & 31u);

            float sr = r00*w00 + r10*w10 + r01*w01 + r11*w11;
            float sg = g00*w00 + g10*w10 + g01*w01 + g11*w11;
            float sb = b00*w00 + b10*w10 + b01*w01 + b11*w11;

            bool m = !((sr == 0.0f) && (sg == 0.0f) && (sb == 0.0f));

            float d0 = fmaf(sr, 1.0f / 31.0f, -r0);
            float d1 = fmaf(sg, 1.0f / 63.0f, -r1);
            float d2 = fmaf(sb, 1.0f / 31.0f, -r2);
            float per = sqrtf(d0*d0 + d1*d1 + d2*d2);

            accs[nb] += m ? per : 0.0f;
            cnl[nb]  += m ? 1.0f : 0.0f;
        }
    }

    // wave(64) shuffle reduce per batch, then LDS across 4 waves, then atomics
    __shared__ float lsum[4][NB], lcnt[4][NB];
    int wid = tid >> 6;
    int lane = tid & 63;
    #pragma unroll
    for (int nb = 0; nb < NB; ++nb) {
        float a = accs[nb], c = cnl[nb];
        #pragma unroll
        for (int off = 32; off > 0; off >>= 1) {
            a += __shfl_down(a, off, 64);
            c += __shfl_down(c, off, 64);
        }
        if (lane == 0) { lsum[wid][nb] = a; lcnt[wid][nb] = c; }
    }
    __syncthreads();
    if (tid < NB * 2) {
        int nb = tid & (NB - 1);
        int k = tid >> 3;   // 0 = sum, 1 = cnt
        float v = 0.f;
        #pragma unroll
        for (int w = 0; w < 4; ++w) v += k ? lcnt[w][nb] : lsum[w][nb];
        atomicAdd(k ? &cnts[b0 + nb] : &sums[b0 + nb], v);
    }
}

__global__ void bsl_finalize(const float* __restrict__ sums,
                             const float* __restrict__ cnts,
                             float* __restrict__ out,
                             int B) {
    int b = threadIdx.x;  // 0..63
    float loss = 0.f;
    if (b < B) {
        loss = sums[b] / cnts[b];
        out[1 + b] = loss;
    }
    #pragma unroll
    for (int off = 32; off > 0; off >>= 1)
        loss += __shfl_down(loss, off, 64);
    if (b == 0) out[0] = loss;
}

extern "C" void kernel_launch(void* const* d_in, const int* in_sizes, int n_in,
                              void* d_out, int out_size, void* d_ws, size_t ws_size,
                              hipStream_t stream) {
    const float* xyz   = (const float*)d_in[0];
    const float* rgb   = (const float*)d_in[1];
    const float* img   = (const float*)d_in[2];
    const float* trans = (const float*)d_in[3];
    const float* yaw   = (const float*)d_in[4];
    const float* pitch = (const float*)d_in[5];
    const float* roll  = (const float*)d_in[6];
    float* out = (float*)d_out;

    const int n_pts = in_sizes[0] / 3;      // 200000
    const int B     = in_sizes[3] / 3;      // 32

    float* ws   = (float*)d_ws;
    float* rm   = ws;               // 9*B floats
    float* sums = ws + 9 * B;       // B floats
    float* cnts = ws + 10 * B;      // B floats
    uint32_t* vp2 = (uint32_t*)((char*)d_ws + 2048);  // 4 MB

    bsl_pack_setup<<<((IMG_H / 2) * (IMG_W / 4) + 255) / 256, 256, 0, stream>>>(
        img, vp2, yaw, pitch, roll, rm, sums, cnts, B);

    dim3 grid((n_pts + 255) / 256, B / NB);
    bsl_main<<<grid, 256, 0, stream>>>(xyz, rgb, vp2, trans, rm, sums, cnts, n_pts);

    bsl_finalize<<<1, 64, 0, stream>>>(sums, cnts, out, B);
}